// Round 15
// baseline (268.585 us; speedup 1.0000x reference)
//
#include <hip/hip_runtime.h>
#include <hip/hip_bf16.h>

#define NV 23
#define NTOT 16384
#define FLAT (NV * 256)    // 5888 floats per slab
#define FLAT4 (FLAT / 4)   // 1472
#define CH 184             // f32x4 per wave (1472/8)
#define NS 3               // reg slots per chunk (64+64+56)
#define SLAB 23552         // slab bytes

// stats: X8'[4]@0 (32768, fp8) | raw[2]@32768 (47104) -> 79872 B => 2 blocks/CU
// grid 512 x NB0=32
#define NB0 32
#define ROFF0 32768
// write: X'[2]@0 (32768) | raw[3]@32768 (70656) | O@103424 -> 126976, grid 256 x NB1=64
#define NB1 64
#define ROFF1 32768
#define OOFF1 103424

#define NPART 512
#define WT8_OFF 248832
#define TAB8_OFF 314368
#define PSUM_OFF 337920
#define PSSQ_OFF (PSUM_OFF + NPART * FLAT * 4)
#define WS_NEED (PSSQ_OFF + NPART * FLAT * 4)

typedef short s16x8 __attribute__((ext_vector_type(8)));
typedef float f32x4 __attribute__((ext_vector_type(4)));
typedef unsigned u32x4 __attribute__((ext_vector_type(4)));
typedef long long i64t;

// x/23 for 0 <= x < 61681
__device__ __forceinline__ int divNV(int x) { return (int)(((unsigned)x * 45591u) >> 20); }
// f32 -> bf16 bits, RNE
__device__ __forceinline__ unsigned f2bf(float f) {
  unsigned u = __float_as_uint(f);
  u += 0x7fffu + ((u >> 16) & 1u);
  return u >> 16;
}
// X' column swizzle (16-B granules): 6 distinct groups for w-strides of 4
// (form writes ~conflict-free), reads uniform across bank cycle.
__device__ __forceinline__ int fsw(int w) { return ((w + (w >> 3)) * 3) & 7; }

// async global->LDS DMA, 16B per lane (lds dest wave-uniform, HW adds lane*16)
__device__ __forceinline__ void gl_lds16(const void* g, void* l) {
  __builtin_amdgcn_global_load_lds(
      (const __attribute__((address_space(1))) unsigned*)(unsigned long long)(uintptr_t)g,
      (__attribute__((address_space(3))) unsigned*)(unsigned)(uintptr_t)l, 16, 0, 0);
}

// ws: Wt@0 | tab@131072 | sum@154624 | ssq@178176 | An2@201728 | Bn2@225280
//     | Wt8@248832 | tab8@314368 | psum@337920 | pssq -> ~24.5MB (atomic fallback if less)
__global__ void k_prep(const float* __restrict__ W, const float* __restrict__ mask,
                       short* __restrict__ Wt, char* __restrict__ Wt8,
                       unsigned* __restrict__ tab, unsigned* __restrict__ tab8,
                       float* __restrict__ sums) {
  int idx = blockIdx.x * 256 + threadIdx.x;  // grid 256 -> 65536
  int d = idx >> 8, c = idx & 255;
  float wv = W[c * 256 + d];
  Wt[idx] = (short)f2bf(wv);                 // W^T bf16: Wt[d][c]
  Wt8[idx] = (char)__builtin_amdgcn_cvt_pk_fp8_f32(wv, wv, 0, false);  // e4m3
  if (idx < FLAT) {
    // p = idx = c*23 + v ; w = (v - c) mod 23
    int cc = divNV(idx);
    int v = idx - NV * cc;
    int cm = cc - NV * divNV(cc);
    int w = v - cm; w += (w >> 31) & NV;
    unsigned m2b = f2bf(tanhf(mask[(w << 8) + cc]) + 1.0f) << 16;
    tab[idx]  = m2b | (unsigned)((w << 9) + ((cc << 1) ^ (fsw(w) << 4)));  // bf16 X'
    tab8[idx] = m2b | (unsigned)((w << 8) + (cc ^ (fsw(w) << 4)));          // fp8 X'
  }
  if (idx < 2 * FLAT) sums[idx] = 0.0f;      // zero sum+ssq (atomic fallback)
}

// grid 92 x 256. Partial path: reduce NPART per-block partials; else sum/ssq.
__global__ void k_finalize(const float* __restrict__ sum, const float* __restrict__ ssq,
                           const float* __restrict__ psum, const float* __restrict__ pssq,
                           const float* __restrict__ bnw, const float* __restrict__ bnb,
                           float* __restrict__ An2, float* __restrict__ Bn2) {
  __shared__ float red[2][4][64];
  const int t = threadIdx.x;
  const int f0 = blockIdx.x * 64;
  if (psum) {
    const int fl = t & 63, c = t >> 6;   // 4 chunks x 128 partials each
    float S = 0.f, Q = 0.f;
    for (int b = 0; b < NPART / 4; ++b) {
      S += psum[(size_t)(c * (NPART / 4) + b) * FLAT + f0 + fl];
      Q += pssq[(size_t)(c * (NPART / 4) + b) * FLAT + f0 + fl];
    }
    red[0][c][fl] = S;
    red[1][c][fl] = Q;
    __syncthreads();
  }
  if (t < 64) {
    int idx = f0 + t;
    float S, Q;
    if (psum) {
      S = red[0][0][t] + red[0][1][t] + red[0][2][t] + red[0][3][t];
      Q = red[1][0][t] + red[1][1][t] + red[1][2][t] + red[1][3][t];
    } else {
      S = sum[idx]; Q = ssq[idx];
    }
    int w = idx >> 8, d = idx & 255;
    float mean = S * (1.0f / NTOT);
    float var  = Q * (1.0f / NTOT) - mean * mean;
    float inv  = rsqrtf(var + 1e-5f);
    int i = w + d; i -= NV * divNV(i);       // out-shift row i = (w+d) % 23
    float a = inv * bnw[i * 256 + d];
    An2[d * NV + i] = a;
    Bn2[d * NV + i] = bnb[i * 256 + d] - mean * a;
  }
}

// Stats FP8, R15: 79872 B LDS -> 2 blocks/CU (4 waves/SIMD). Co-resident
// blocks at different phase positions absorb each other's barrier/lgkm
// stalls (R8-R14 lockstep at 1 block/CU had nothing to run during waits).
// 1 slab/phase, raw[2] (DMA slack = 1 phase ~3000cy >> 900cy HBM latency),
// X8'[4], A-fragments preloaded before the MFMA burst.
__global__ __launch_bounds__(512) void k_stats(
    const float* __restrict__ x0, const char* __restrict__ Wt8,
    const unsigned* __restrict__ tab8, float* __restrict__ sum, float* __restrict__ ssq,
    float* __restrict__ psum, float* __restrict__ pssq) {
  __shared__ char smem[79872];  // X8'[4] | raw[2]

  const int tid = threadIdx.x;
  const int lane = tid & 63;
  const int wv = tid >> 6;
  const int l15 = lane & 15;
  const int lg = lane >> 4;
  const int d0 = wv * 32;
  const int ch0 = wv * CH;
  const int fr0 = fsw(l15) << 4;
  const int fr1 = fsw(16 + l15) << 4;

  // B fragments fp8 (32 VGPR): B[k=c][n=d] = Wt8[d][c], 8B per kt
  i64t bfr8[2][8];
#pragma unroll
  for (int nt = 0; nt < 2; ++nt)
#pragma unroll
    for (int kt = 0; kt < 8; ++kt)
      bfr8[nt][kt] = *(const i64t*)(Wt8 + (d0 + nt * 16 + l15) * 256 + kt * 32 + lg * 8);

  u32x4 tbr[NS];
#pragma unroll
  for (int s = 0; s < NS; ++s)
    if (s * 64 + lane < CH) tbr[s] = *(const u32x4*)(tab8 + 4 * (ch0 + s * 64 + lane));

  // zero pad rows 23..31 of the 4 X8' buffers (2304B each)
  for (int i = tid; i < 2304; i += 512) {
    int b = i / 576;
    *(int*)(smem + b * 8192 + 5888 + (i - b * 576) * 4) = 0;
  }

  float s1[2][2][4], s2[2][2][4];
#pragma unroll
  for (int mt = 0; mt < 2; ++mt)
#pragma unroll
    for (int nt = 0; nt < 2; ++nt)
#pragma unroll
      for (int r = 0; r < 4; ++r) { s1[mt][nt][r] = 0.f; s2[mt][nt][r] = 0.f; }

  const int nbase = blockIdx.x * NB0;

  auto stage = [&](int T) {  // 23 exact DMAs for slab T -> raw[T&1]
    if (T >= NB0) return;
    const char* gs = (const char*)(x0 + (size_t)(nbase + T) * FLAT);
    char* lb = smem + ROFF0 + (T & 1) * SLAB;
    gl_lds16(gs + (wv << 10) + lane * 16, lb + (wv << 10));
    gl_lds16(gs + ((8 + wv) << 10) + lane * 16, lb + ((8 + wv) << 10));
    if (wv < 7)
      gl_lds16(gs + ((16 + wv) << 10) + lane * 16, lb + ((16 + wv) << 10));
  };
  auto form = [&](int T) {  // fp8 X' into X8[T%4] from raw[T&1]
    if (T >= NB0) return;
    const char* rb = smem + ROFF0 + (T & 1) * SLAB;
    char* xb = smem + (T % 4) * 8192;
#pragma unroll
    for (int s = 0; s < NS; ++s)
      if (s * 64 + lane < CH) {
        f32x4 xv = *(const f32x4*)(rb + (ch0 + s * 64 + lane) * 16);
        u32x4 tb = tbr[s];
        float v0 = xv[0] * __uint_as_float(tb[0] & 0xffff0000u);
        float v1 = xv[1] * __uint_as_float(tb[1] & 0xffff0000u);
        float v2 = xv[2] * __uint_as_float(tb[2] & 0xffff0000u);
        float v3 = xv[3] * __uint_as_float(tb[3] & 0xffff0000u);
        int u01 = __builtin_amdgcn_cvt_pk_fp8_f32(v0, v1, 0, false);
        int u23 = __builtin_amdgcn_cvt_pk_fp8_f32(v2, v3, 0, false);
        xb[tb[0] & 0xffffu] = (char)u01;
        xb[tb[1] & 0xffffu] = (char)(u01 >> 8);
        xb[tb[2] & 0xffffu] = (char)u23;
        xb[tb[3] & 0xffffu] = (char)(u23 >> 8);
      }
  };
  auto mstep = [&](int T, f32x4 (*acc)[2]) {  // y = X8'(T) * W8, A preloaded
    const char* xb = smem + (T % 4) * 8192;
    i64t a0[8], a1[8];
#pragma unroll
    for (int kt = 0; kt < 8; ++kt) {
      a0[kt] = *(const i64t*)(xb + (l15 << 8) + ((kt * 32 + lg * 8) ^ fr0));
      a1[kt] = *(const i64t*)(xb + ((16 + l15) << 8) + ((kt * 32 + lg * 8) ^ fr1));
    }
#pragma unroll
    for (int kt = 0; kt < 8; ++kt) {
#pragma unroll
      for (int nt = 0; nt < 2; ++nt) {
        acc[0][nt] = __builtin_amdgcn_mfma_f32_16x16x32_fp8_fp8(a0[kt], bfr8[nt][kt], acc[0][nt], 0, 0, 0);
        acc[1][nt] = __builtin_amdgcn_mfma_f32_16x16x32_fp8_fp8(a1[kt], bfr8[nt][kt], acc[1][nt], 0, 0, 0);
      }
    }
  };
  auto bar = []() {
    asm volatile("s_waitcnt lgkmcnt(0)" ::: "memory");
    __builtin_amdgcn_s_barrier();
    asm volatile("" ::: "memory");
  };

  // prologue
  stage(0); stage(1);
  asm volatile("s_waitcnt vmcnt(0)" ::: "memory");
  bar();
  form(0);

  for (int t = 0; t < NB0; ++t) {
    asm volatile("s_waitcnt vmcnt(0)" ::: "memory");  // DMA(t+1) landed
    bar();  // all waves' DMA(t+1) + form(t) visible; prev readers done
    stage(t + 2);  // -> raw[t&1], last read by form(t) in phase t-1
    f32x4 acc[2][2];
    __builtin_amdgcn_s_setprio(1);
#pragma unroll
    for (int mt = 0; mt < 2; ++mt)
#pragma unroll
      for (int nt = 0; nt < 2; ++nt) acc[mt][nt] = (f32x4){0.f, 0.f, 0.f, 0.f};
    mstep(t, acc);
    __builtin_amdgcn_s_setprio(0);
#pragma unroll
    for (int mt = 0; mt < 2; ++mt)
#pragma unroll
      for (int nt = 0; nt < 2; ++nt)
#pragma unroll
        for (int r = 0; r < 4; ++r) {
          float y = acc[mt][nt][r];
          s1[mt][nt][r] += y;
          s2[mt][nt][r] += y * y;
        }
    form(t + 1);  // raw[(t+1)&1] -> X8'[(t+1)%4]
  }
  if (psum) {
    float* ps = psum + (size_t)blockIdx.x * FLAT;
    float* pq = pssq + (size_t)blockIdx.x * FLAT;
#pragma unroll
    for (int mt = 0; mt < 2; ++mt)
#pragma unroll
      for (int nt = 0; nt < 2; ++nt)
#pragma unroll
        for (int r = 0; r < 4; ++r) {
          int w = mt * 16 + lg * 4 + r;
          if (w < NV) {
            int d = d0 + nt * 16 + l15;
            __builtin_nontemporal_store(s1[mt][nt][r], ps + (w << 8) + d);
            __builtin_nontemporal_store(s2[mt][nt][r], pq + (w << 8) + d);
          }
        }
  } else {
#pragma unroll
    for (int mt = 0; mt < 2; ++mt)
#pragma unroll
      for (int nt = 0; nt < 2; ++nt)
#pragma unroll
        for (int r = 0; r < 4; ++r) {
          int w = mt * 16 + lg * 4 + r;
          if (w < NV) {
            int d = d0 + nt * 16 + l15;
            atomicAdd(sum + (w << 8) + d, s1[mt][nt][r]);
            atomicAdd(ssq + (w << 8) + d, s2[mt][nt][r]);
          }
        }
  }
}

// Output pass: bf16, R14 verbatim (near HBM floor).
__global__ __launch_bounds__(512) void k_write(
    const float* __restrict__ x0, const short* __restrict__ Wt,
    const unsigned* __restrict__ tab,
    const float* __restrict__ An2, const float* __restrict__ Bn2,
    float* __restrict__ out) {
  __shared__ char smem[126976];  // X'[2] | raw[3] | O
  float* O = (float*)(smem + OOFF1);

  const int tid = threadIdx.x;
  const int lane = tid & 63;
  const int wv = tid >> 6;
  const int l15 = lane & 15;
  const int lg = lane >> 4;
  const int d0 = wv * 32;
  const int ch0 = wv * CH;
  const int fr0 = fsw(l15) << 4;
  const int fr1 = fsw(16 + l15) << 4;

  s16x8 bfr[2][8];
#pragma unroll
  for (int nt = 0; nt < 2; ++nt)
#pragma unroll
    for (int kt = 0; kt < 8; ++kt)
      bfr[nt][kt] = *(const s16x8*)(Wt + (d0 + nt * 16 + l15) * 256 + kt * 32 + lg * 8);

  u32x4 tbr[NS];
#pragma unroll
  for (int s = 0; s < NS; ++s)
    if (s * 64 + lane < CH) tbr[s] = *(const u32x4*)(tab + 4 * (ch0 + s * 64 + lane));

  f32x4 anr[NS], bnr[NS];
#pragma unroll
  for (int s = 0; s < NS; ++s)
    if (s * 64 + lane < CH) {
      anr[s] = *(const f32x4*)(An2 + 4 * (ch0 + s * 64 + lane));
      bnr[s] = *(const f32x4*)(Bn2 + 4 * (ch0 + s * 64 + lane));
    }

  for (int i = tid; i < 2304; i += 512) {
    int b = i >= 1152;
    *(int*)(smem + b * 16384 + 11776 + (i - b * 1152) * 4) = 0;
  }

  const int nbase = blockIdx.x * NB1;
  auto nmap = [&](int T) { return nbase + (NB1 - 1 - T); };  // reverse: L3 tail

  auto stage = [&](int T) {
    if (T >= NB1) return;
    const char* gs = (const char*)(x0 + (size_t)nmap(T) * FLAT);
    char* lb = smem + ROFF1 + (T % 3) * SLAB;
    gl_lds16(gs + (wv << 10) + lane * 16, lb + (wv << 10));
    gl_lds16(gs + ((8 + wv) << 10) + lane * 16, lb + ((8 + wv) << 10));
    if (wv < 7)
      gl_lds16(gs + ((16 + wv) << 10) + lane * 16, lb + ((16 + wv) << 10));
  };
  auto form = [&](int T) {
    if (T >= NB1) return;
    const char* rb = smem + ROFF1 + (T % 3) * SLAB;
    char* xb = smem + (T & 1) * 16384;
#pragma unroll
    for (int s = 0; s < NS; ++s)
      if (s * 64 + lane < CH) {
        f32x4 xv = *(const f32x4*)(rb + (ch0 + s * 64 + lane) * 16);
        u32x4 tb = tbr[s];
#pragma unroll
        for (int e = 0; e < 4; ++e) {
          unsigned tt = tb[e];
          *(short*)(xb + (tt & 0xffffu)) =
              (short)f2bf(xv[e] * __uint_as_float(tt & 0xffff0000u));
        }
      }
  };
  auto bar = []() {
    asm volatile("s_waitcnt lgkmcnt(0)" ::: "memory");
    __builtin_amdgcn_s_barrier();
    asm volatile("" ::: "memory");
  };

  stage(0); stage(1);
  asm volatile("s_waitcnt vmcnt(0)" ::: "memory");
  bar();
  form(0);

  for (int t = 0; t < NB1; ++t) {
    if (t) asm volatile("s_waitcnt vmcnt(3)" ::: "memory");
    else   asm volatile("s_waitcnt vmcnt(0)" ::: "memory");
    bar();
    stage(t + 2);
    form(t + 1);

    const char* xb = smem + (t & 1) * 16384;
    f32x4 acc[2][2];
#pragma unroll
    for (int mt = 0; mt < 2; ++mt)
#pragma unroll
      for (int nt = 0; nt < 2; ++nt) acc[mt][nt] = (f32x4){0.f, 0.f, 0.f, 0.f};
    __builtin_amdgcn_s_setprio(1);
#pragma unroll
    for (int kt = 0; kt < 8; ++kt) {
      s16x8 af[2];
      af[0] = *(const s16x8*)(xb + (l15 << 9) + ((kt * 64 + lg * 16) ^ fr0));
      af[1] = *(const s16x8*)(xb + ((16 + l15) << 9) + ((kt * 64 + lg * 16) ^ fr1));
#pragma unroll
      for (int mt = 0; mt < 2; ++mt)
#pragma unroll
        for (int nt = 0; nt < 2; ++nt)
          acc[mt][nt] = __builtin_amdgcn_mfma_f32_16x16x32_bf16(
              af[mt], bfr[nt][kt], acc[mt][nt], 0, 0, 0);
    }
    __builtin_amdgcn_s_setprio(0);

#pragma unroll
    for (int mt = 0; mt < 2; ++mt)
#pragma unroll
      for (int nt = 0; nt < 2; ++nt)
#pragma unroll
        for (int r = 0; r < 4; ++r) {
          int w = mt * 16 + lg * 4 + r;
          if (w < NV) {
            int d = d0 + nt * 16 + l15;
            int sj = w + d; sj -= NV * divNV(sj);
            O[d * NV + sj] = acc[mt][nt][r];
          }
        }
    const char* rb = smem + ROFF1 + (t % 3) * SLAB;
    float* og = out + (size_t)nmap(t) * FLAT;
#pragma unroll
    for (int s = 0; s < NS; ++s)
      if (s * 64 + lane < CH) {
        int i = ch0 + s * 64 + lane;
        f32x4 y = *(const f32x4*)(O + 4 * i);
        f32x4 sl = *(const f32x4*)(rb + i * 16);
        f32x4 o;
#pragma unroll
        for (int e = 0; e < 4; ++e)
          o[e] = fmaxf(fmaf(y[e], anr[s][e], bnr[s][e]) + sl[e], 0.0f);
        __builtin_nontemporal_store(o, (f32x4*)og + i);
      }
  }
}

extern "C" void kernel_launch(void* const* d_in, const int* in_sizes, int n_in,
                              void* d_out, int out_size, void* d_ws, size_t ws_size,
                              hipStream_t stream) {
  const float* x0   = (const float*)d_in[0];
  const float* W    = (const float*)d_in[1];
  // d_in[2] = bias: cancels inside BN -> unused
  const float* mask = (const float*)d_in[3];
  const float* bnw  = (const float*)d_in[4];
  const float* bnb  = (const float*)d_in[5];
  // d_in[6], d_in[7] = shift tables: folded into addressing
  float* out = (float*)d_out;

  char* ws = (char*)d_ws;
  short* Wt      = (short*)ws;
  unsigned* tab  = (unsigned*)(ws + 131072);
  float* sum     = (float*)(ws + 154624);
  float* ssq     = (float*)(ws + 178176);
  float* An2     = (float*)(ws + 201728);
  float* Bn2     = (float*)(ws + 225280);
  char* Wt8      = ws + WT8_OFF;
  unsigned* tab8 = (unsigned*)(ws + TAB8_OFF);
  bool part = ws_size >= (size_t)WS_NEED;
  float* psum = part ? (float*)(ws + PSUM_OFF) : nullptr;
  float* pssq = part ? (float*)(ws + PSSQ_OFF) : nullptr;

  k_prep<<<256, 256, 0, stream>>>(W, mask, Wt, Wt8, tab, tab8, sum);
  k_stats<<<512, 512, 0, stream>>>(x0, Wt8, tab8, sum, ssq, psum, pssq);
  k_finalize<<<92, 256, 0, stream>>>(sum, ssq, psum, pssq, bnw, bnb, An2, Bn2);
  k_write<<<256, 512, 0, stream>>>(x0, Wt, tab, An2, Bn2, out);
}

// Round 16
// 241.190 us; speedup vs baseline: 1.1136x; 1.1136x over previous
//
#include <hip/hip_runtime.h>
#include <hip/hip_bf16.h>

#define NV 23
#define NTOT 16384
#define FLAT (NV * 256)    // 5888 floats per slab
#define FLAT4 (FLAT / 4)   // 1472
#define CH 184             // f32x4 per wave (1472/8)
#define NS 3               // reg slots per chunk (64+64+56)
#define SLAB 23552         // slab bytes

// stats: X48[2]@0 (24576, fp8 48x256B pair-tiles) | raw[4]@24576 (94208) -> 118784
// grid 256 x NB0=64 slabs (32 pairs)
#define NB0 64
#define ROFF0 24576
// write: X'[2]@0 (32768) | raw[3]@32768 (70656) | O@103424 -> 126976, grid 256 x NB1=64
#define NB1 64
#define ROFF1 32768
#define OOFF1 103424

#define NPART 256
#define PROWS 48           // psum rows per block (46 used)
#define WT8_OFF 248832
#define TAB8_OFF 314368
#define TAB8B_OFF 337920
#define PSUM_OFF 361472
#define PSSQ_OFF (PSUM_OFF + NPART * PROWS * 256 * 4)
#define WS_NEED (PSSQ_OFF + NPART * PROWS * 256 * 4)

typedef short s16x8 __attribute__((ext_vector_type(8)));
typedef float f32x4 __attribute__((ext_vector_type(4)));
typedef unsigned u32x4 __attribute__((ext_vector_type(4)));
typedef long long i64t;

// x/23 for 0 <= x < 61681
__device__ __forceinline__ int divNV(int x) { return (int)(((unsigned)x * 45591u) >> 20); }
// f32 -> bf16 bits, RNE
__device__ __forceinline__ unsigned f2bf(float f) {
  unsigned u = __float_as_uint(f);
  u += 0x7fffu + ((u >> 16) & 1u);
  return u >> 16;
}
// X' column swizzle (16-B granules): distinct groups for w-strides of 4
// (form writes ~conflict-free), 16-lane read groups 8 distinct slots (2-way, free).
__device__ __forceinline__ int fsw(int w) { return ((w + (w >> 3)) * 3) & 7; }

// async global->LDS DMA, 16B per lane (lds dest wave-uniform, HW adds lane*16)
__device__ __forceinline__ void gl_lds16(const void* g, void* l) {
  __builtin_amdgcn_global_load_lds(
      (const __attribute__((address_space(1))) unsigned*)(unsigned long long)(uintptr_t)g,
      (__attribute__((address_space(3))) unsigned*)(unsigned)(uintptr_t)l, 16, 0, 0);
}

// ws: Wt@0 | tab@131072 | sum@154624 | ssq@178176 | An2@201728 | Bn2@225280
//     | Wt8@248832 | tab8@314368 | tab8b@337920 | psum@361472 | pssq -> ~25.5MB
__global__ void k_prep(const float* __restrict__ W, const float* __restrict__ mask,
                       short* __restrict__ Wt, char* __restrict__ Wt8,
                       unsigned* __restrict__ tab, unsigned* __restrict__ tab8,
                       unsigned* __restrict__ tab8b, float* __restrict__ sums) {
  int idx = blockIdx.x * 256 + threadIdx.x;  // grid 256 -> 65536
  int d = idx >> 8, c = idx & 255;
  float wv = W[c * 256 + d];
  Wt[idx] = (short)f2bf(wv);                 // W^T bf16: Wt[d][c]
  Wt8[idx] = (char)__builtin_amdgcn_cvt_pk_fp8_f32(wv, wv, 0, false);  // e4m3
  if (idx < FLAT) {
    // p = idx = c*23 + v ; w = (v - c) mod 23
    int cc = divNV(idx);
    int v = idx - NV * cc;
    int cm = cc - NV * divNV(cc);
    int w = v - cm; w += (w >> 31) & NV;
    unsigned m2b = f2bf(tanhf(mask[(w << 8) + cc]) + 1.0f) << 16;
    tab[idx]   = m2b | (unsigned)((w << 9) + ((cc << 1) ^ (fsw(w) << 4)));      // bf16 X'
    tab8[idx]  = m2b | (unsigned)((w << 8) + (cc ^ (fsw(w) << 4)));             // fp8 row w
    tab8b[idx] = m2b | (unsigned)(((w + NV) << 8) + (cc ^ (fsw(w + NV) << 4))); // fp8 row w+23
  }
  if (idx < 2 * FLAT) sums[idx] = 0.0f;      // zero sum+ssq (atomic fallback)
}

// grid 92 x 256. Partial path: P[b][row<48][d]; feature (w,d) = rows w and w+23.
__global__ void k_finalize(const float* __restrict__ sum, const float* __restrict__ ssq,
                           const float* __restrict__ psum, const float* __restrict__ pssq,
                           const float* __restrict__ bnw, const float* __restrict__ bnb,
                           float* __restrict__ An2, float* __restrict__ Bn2) {
  __shared__ float red[2][4][64];
  const int t = threadIdx.x;
  const int f0 = blockIdx.x * 64;
  const int wq = f0 >> 8;                  // uniform w for this block
  const int dq = (f0 & 255);
  if (psum) {
    const int fl = t & 63, c = t >> 6;     // 4 chunks x 64 partials each
    size_t oA = (size_t)(wq << 8) + dq + fl;
    size_t oB = (size_t)((wq + NV) << 8) + dq + fl;
    float S = 0.f, Q = 0.f;
    for (int b = 0; b < 64; ++b) {
      size_t base = (size_t)(c * 64 + b) * (PROWS * 256);
      S += psum[base + oA] + psum[base + oB];
      Q += pssq[base + oA] + pssq[base + oB];
    }
    red[0][c][fl] = S;
    red[1][c][fl] = Q;
    __syncthreads();
  }
  if (t < 64) {
    int idx = f0 + t;
    float S, Q;
    if (psum) {
      S = red[0][0][t] + red[0][1][t] + red[0][2][t] + red[0][3][t];
      Q = red[1][0][t] + red[1][1][t] + red[1][2][t] + red[1][3][t];
    } else {
      S = sum[idx]; Q = ssq[idx];
    }
    int w = idx >> 8, d = idx & 255;
    float mean = S * (1.0f / NTOT);
    float var  = Q * (1.0f / NTOT) - mean * mean;
    float inv  = rsqrtf(var + 1e-5f);
    int i = w + d; i -= NV * divNV(i);       // out-shift row i = (w+d) % 23
    float a = inv * bnw[i * 256 + d];
    An2[d * NV + i] = a;
    Bn2[d * NV + i] = bnb[i * 256 + d] - mean * a;
  }
}

// Stats FP8, R16: two slabs batched into one M=48 A-tile (rows 0-22 slab a,
// 23-45 slab b, 46-47 zero). Kills the 23->32 pad waste: 48 MFMAs + 12KB
// A-reads per pair vs 64 + 16KB. Phase = 1 pair (2 slabs), R14 cadence.
__global__ __launch_bounds__(512) void k_stats(
    const float* __restrict__ x0, const char* __restrict__ Wt8,
    const unsigned* __restrict__ tab8, const unsigned* __restrict__ tab8b,
    float* __restrict__ sum, float* __restrict__ ssq,
    float* __restrict__ psum, float* __restrict__ pssq) {
  __shared__ char smem[118784];  // X48[2] | raw[4]

  const int tid = threadIdx.x;
  const int lane = tid & 63;
  const int wv = tid >> 6;
  const int l15 = lane & 15;
  const int lg = lane >> 4;
  const int d0 = wv * 32;
  const int ch0 = wv * CH;
  const int fr0 = fsw(l15) << 4;          // read swizzle rows l15, 16+l15, 32+l15
  const int fr1 = fsw(16 + l15) << 4;
  const int fr2 = fsw(32 + l15) << 4;

  // B fragments fp8 (32 VGPR): B[k=c][n=d] = Wt8[d][c]
  i64t bfr8[2][8];
#pragma unroll
  for (int nt = 0; nt < 2; ++nt)
#pragma unroll
    for (int kt = 0; kt < 8; ++kt)
      bfr8[nt][kt] = *(const i64t*)(Wt8 + (d0 + nt * 16 + l15) * 256 + kt * 32 + lg * 8);

  u32x4 tbrA[NS], tbrB[NS];
#pragma unroll
  for (int s = 0; s < NS; ++s)
    if (s * 64 + lane < CH) {
      tbrA[s] = *(const u32x4*)(tab8 + 4 * (ch0 + s * 64 + lane));
      tbrB[s] = *(const u32x4*)(tab8b + 4 * (ch0 + s * 64 + lane));
    }

  // zero rows 46,47 of both X48 buffers (512B each, never written again)
  if (tid < 256) {
    int b = tid >> 7;
    *(int*)(smem + b * 12288 + 11776 + (tid & 127) * 4) = 0;
  }

  float s1[3][2][4], s2[3][2][4];
#pragma unroll
  for (int mt = 0; mt < 3; ++mt)
#pragma unroll
    for (int nt = 0; nt < 2; ++nt)
#pragma unroll
      for (int r = 0; r < 4; ++r) { s1[mt][nt][r] = 0.f; s2[mt][nt][r] = 0.f; }

  const int nbase = blockIdx.x * NB0;

  auto stage = [&](int T) {  // 23 exact DMAs for slab T -> raw[T%4]
    if (T >= NB0) return;
    const char* gs = (const char*)(x0 + (size_t)(nbase + T) * FLAT);
    char* lb = smem + ROFF0 + (T % 4) * SLAB;
    gl_lds16(gs + (wv << 10) + lane * 16, lb + (wv << 10));
    gl_lds16(gs + ((8 + wv) << 10) + lane * 16, lb + ((8 + wv) << 10));
    if (wv < 7)
      gl_lds16(gs + ((16 + wv) << 10) + lane * 16, lb + ((16 + wv) << 10));
  };
  auto formpair = [&](int P) {  // slabs 2P,2P+1 -> X48[P&1]
    if (2 * P >= NB0) return;
    const char* ra = smem + ROFF0 + ((2 * P) % 4) * SLAB;
    const char* rb = smem + ROFF0 + ((2 * P + 1) % 4) * SLAB;
    char* xb = smem + (P & 1) * 12288;
#pragma unroll
    for (int s = 0; s < NS; ++s)
      if (s * 64 + lane < CH) {
        f32x4 xa = *(const f32x4*)(ra + (ch0 + s * 64 + lane) * 16);
        f32x4 xv = *(const f32x4*)(rb + (ch0 + s * 64 + lane) * 16);
        u32x4 ta = tbrA[s], tb = tbrB[s];
#pragma unroll
        for (int e = 0; e < 4; e += 2) {
          float a0 = xa[e] * __uint_as_float(ta[e] & 0xffff0000u);
          float a1 = xa[e + 1] * __uint_as_float(ta[e + 1] & 0xffff0000u);
          float b0 = xv[e] * __uint_as_float(tb[e] & 0xffff0000u);
          float b1 = xv[e + 1] * __uint_as_float(tb[e + 1] & 0xffff0000u);
          int ua = __builtin_amdgcn_cvt_pk_fp8_f32(a0, a1, 0, false);
          int ub = __builtin_amdgcn_cvt_pk_fp8_f32(b0, b1, 0, false);
          xb[ta[e] & 0xffffu] = (char)ua;
          xb[ta[e + 1] & 0xffffu] = (char)(ua >> 8);
          xb[tb[e] & 0xffffu] = (char)ub;
          xb[tb[e + 1] & 0xffffu] = (char)(ub >> 8);
        }
      }
  };
  auto mstep = [&](int P, f32x4 (*acc)[2]) {  // y48 = X48[P&1] * W8
    const char* xb = smem + (P & 1) * 12288;
#pragma unroll
    for (int mt = 0; mt < 3; ++mt) {
      const int row = mt * 16 + l15;
      const int fr = mt == 0 ? fr0 : (mt == 1 ? fr1 : fr2);
      i64t a[8];
#pragma unroll
      for (int kt = 0; kt < 8; ++kt)
        a[kt] = *(const i64t*)(xb + (row << 8) + ((kt * 32 + lg * 8) ^ fr));
#pragma unroll
      for (int kt = 0; kt < 8; ++kt)
#pragma unroll
        for (int nt = 0; nt < 2; ++nt)
          acc[mt][nt] = __builtin_amdgcn_mfma_f32_16x16x32_fp8_fp8(
              a[kt], bfr8[nt][kt], acc[mt][nt], 0, 0, 0);
    }
  };
  auto bar = []() {
    asm volatile("s_waitcnt lgkmcnt(0)" ::: "memory");
    __builtin_amdgcn_s_barrier();
    asm volatile("" ::: "memory");
  };

  // prologue: 4 slabs in flight, form pair 0
  stage(0); stage(1); stage(2); stage(3);
  asm volatile("s_waitcnt vmcnt(0)" ::: "memory");
  bar();
  formpair(0);

  for (int u = 0; u < NB0 / 2; ++u) {
    asm volatile("s_waitcnt vmcnt(0)" ::: "memory");  // prev phase's slabs landed
    bar();  // all waves' DMAs + formpair(u) visible; prev X48 readers done
    stage(2 * u + 4); stage(2 * u + 5);
    formpair(u + 1);
    f32x4 acc[3][2];
    __builtin_amdgcn_s_setprio(1);
#pragma unroll
    for (int mt = 0; mt < 3; ++mt)
#pragma unroll
      for (int nt = 0; nt < 2; ++nt) acc[mt][nt] = (f32x4){0.f, 0.f, 0.f, 0.f};
    mstep(u, acc);
    __builtin_amdgcn_s_setprio(0);
#pragma unroll
    for (int mt = 0; mt < 3; ++mt)
#pragma unroll
      for (int nt = 0; nt < 2; ++nt)
#pragma unroll
        for (int r = 0; r < 4; ++r) {
          float y = acc[mt][nt][r];
          s1[mt][nt][r] += y;
          s2[mt][nt][r] += y * y;
        }
  }

  if (psum) {
    float* ps = psum + (size_t)blockIdx.x * (PROWS * 256);
    float* pq = pssq + (size_t)blockIdx.x * (PROWS * 256);
#pragma unroll
    for (int mt = 0; mt < 3; ++mt)
#pragma unroll
      for (int nt = 0; nt < 2; ++nt)
#pragma unroll
        for (int r = 0; r < 4; ++r) {
          int row = mt * 16 + lg * 4 + r;
          if (row < 46) {
            int d = d0 + nt * 16 + l15;
            __builtin_nontemporal_store(s1[mt][nt][r], ps + (row << 8) + d);
            __builtin_nontemporal_store(s2[mt][nt][r], pq + (row << 8) + d);
          }
        }
  } else {
#pragma unroll
    for (int mt = 0; mt < 3; ++mt)
#pragma unroll
      for (int nt = 0; nt < 2; ++nt)
#pragma unroll
        for (int r = 0; r < 4; ++r) {
          int row = mt * 16 + lg * 4 + r;
          if (row < 46) {
            int w = row - (row >= NV ? NV : 0);
            int d = d0 + nt * 16 + l15;
            atomicAdd(sum + (w << 8) + d, s1[mt][nt][r]);
            atomicAdd(ssq + (w << 8) + d, s2[mt][nt][r]);
          }
        }
  }
}

// Output pass: bf16, R14 verbatim (near HBM floor).
__global__ __launch_bounds__(512) void k_write(
    const float* __restrict__ x0, const short* __restrict__ Wt,
    const unsigned* __restrict__ tab,
    const float* __restrict__ An2, const float* __restrict__ Bn2,
    float* __restrict__ out) {
  __shared__ char smem[126976];  // X'[2] | raw[3] | O
  float* O = (float*)(smem + OOFF1);

  const int tid = threadIdx.x;
  const int lane = tid & 63;
  const int wv = tid >> 6;
  const int l15 = lane & 15;
  const int lg = lane >> 4;
  const int d0 = wv * 32;
  const int ch0 = wv * CH;
  const int fr0 = fsw(l15) << 4;
  const int fr1 = fsw(16 + l15) << 4;

  s16x8 bfr[2][8];
#pragma unroll
  for (int nt = 0; nt < 2; ++nt)
#pragma unroll
    for (int kt = 0; kt < 8; ++kt)
      bfr[nt][kt] = *(const s16x8*)(Wt + (d0 + nt * 16 + l15) * 256 + kt * 32 + lg * 8);

  u32x4 tbr[NS];
#pragma unroll
  for (int s = 0; s < NS; ++s)
    if (s * 64 + lane < CH) tbr[s] = *(const u32x4*)(tab + 4 * (ch0 + s * 64 + lane));

  f32x4 anr[NS], bnr[NS];
#pragma unroll
  for (int s = 0; s < NS; ++s)
    if (s * 64 + lane < CH) {
      anr[s] = *(const f32x4*)(An2 + 4 * (ch0 + s * 64 + lane));
      bnr[s] = *(const f32x4*)(Bn2 + 4 * (ch0 + s * 64 + lane));
    }

  for (int i = tid; i < 2304; i += 512) {
    int b = i >= 1152;
    *(int*)(smem + b * 16384 + 11776 + (i - b * 1152) * 4) = 0;
  }

  const int nbase = blockIdx.x * NB1;
  auto nmap = [&](int T) { return nbase + (NB1 - 1 - T); };  // reverse: L3 tail

  auto stage = [&](int T) {
    if (T >= NB1) return;
    const char* gs = (const char*)(x0 + (size_t)nmap(T) * FLAT);
    char* lb = smem + ROFF1 + (T % 3) * SLAB;
    gl_lds16(gs + (wv << 10) + lane * 16, lb + (wv << 10));
    gl_lds16(gs + ((8 + wv) << 10) + lane * 16, lb + ((8 + wv) << 10));
    if (wv < 7)
      gl_lds16(gs + ((16 + wv) << 10) + lane * 16, lb + ((16 + wv) << 10));
  };
  auto form = [&](int T) {
    if (T >= NB1) return;
    const char* rb = smem + ROFF1 + (T % 3) * SLAB;
    char* xb = smem + (T & 1) * 16384;
#pragma unroll
    for (int s = 0; s < NS; ++s)
      if (s * 64 + lane < CH) {
        f32x4 xv = *(const f32x4*)(rb + (ch0 + s * 64 + lane) * 16);
        u32x4 tb = tbr[s];
#pragma unroll
        for (int e = 0; e < 4; ++e) {
          unsigned tt = tb[e];
          *(short*)(xb + (tt & 0xffffu)) =
              (short)f2bf(xv[e] * __uint_as_float(tt & 0xffff0000u));
        }
      }
  };
  auto bar = []() {
    asm volatile("s_waitcnt lgkmcnt(0)" ::: "memory");
    __builtin_amdgcn_s_barrier();
    asm volatile("" ::: "memory");
  };

  stage(0); stage(1);
  asm volatile("s_waitcnt vmcnt(0)" ::: "memory");
  bar();
  form(0);

  for (int t = 0; t < NB1; ++t) {
    if (t) asm volatile("s_waitcnt vmcnt(3)" ::: "memory");
    else   asm volatile("s_waitcnt vmcnt(0)" ::: "memory");
    bar();
    stage(t + 2);
    form(t + 1);

    const char* xb = smem + (t & 1) * 16384;
    f32x4 acc[2][2];
#pragma unroll
    for (int mt = 0; mt < 2; ++mt)
#pragma unroll
      for (int nt = 0; nt < 2; ++nt) acc[mt][nt] = (f32x4){0.f, 0.f, 0.f, 0.f};
    __builtin_amdgcn_s_setprio(1);
#pragma unroll
    for (int kt = 0; kt < 8; ++kt) {
      s16x8 af[2];
      af[0] = *(const s16x8*)(xb + (l15 << 9) + ((kt * 64 + lg * 16) ^ fr0));
      af[1] = *(const s16x8*)(xb + ((16 + l15) << 9) + ((kt * 64 + lg * 16) ^ fr1));
#pragma unroll
      for (int mt = 0; mt < 2; ++mt)
#pragma unroll
        for (int nt = 0; nt < 2; ++nt)
          acc[mt][nt] = __builtin_amdgcn_mfma_f32_16x16x32_bf16(
              af[mt], bfr[nt][kt], acc[mt][nt], 0, 0, 0);
    }
    __builtin_amdgcn_s_setprio(0);

#pragma unroll
    for (int mt = 0; mt < 2; ++mt)
#pragma unroll
      for (int nt = 0; nt < 2; ++nt)
#pragma unroll
        for (int r = 0; r < 4; ++r) {
          int w = mt * 16 + lg * 4 + r;
          if (w < NV) {
            int d = d0 + nt * 16 + l15;
            int sj = w + d; sj -= NV * divNV(sj);
            O[d * NV + sj] = acc[mt][nt][r];
          }
        }
    const char* rb = smem + ROFF1 + (t % 3) * SLAB;
    float* og = out + (size_t)nmap(t) * FLAT;
#pragma unroll
    for (int s = 0; s < NS; ++s)
      if (s * 64 + lane < CH) {
        int i = ch0 + s * 64 + lane;
        f32x4 y = *(const f32x4*)(O + 4 * i);
        f32x4 sl = *(const f32x4*)(rb + i * 16);
        f32x4 o;
#pragma unroll
        for (int e = 0; e < 4; ++e)
          o[e] = fmaxf(fmaf(y[e], anr[s][e], bnr[s][e]) + sl[e], 0.0f);
        __builtin_nontemporal_store(o, (f32x4*)og + i);
      }
  }
}

extern "C" void kernel_launch(void* const* d_in, const int* in_sizes, int n_in,
                              void* d_out, int out_size, void* d_ws, size_t ws_size,
                              hipStream_t stream) {
  const float* x0   = (const float*)d_in[0];
  const float* W    = (const float*)d_in[1];
  // d_in[2] = bias: cancels inside BN -> unused
  const float* mask = (const float*)d_in[3];
  const float* bnw  = (const float*)d_in[4];
  const float* bnb  = (const float*)d_in[5];
  // d_in[6], d_in[7] = shift tables: folded into addressing
  float* out = (float*)d_out;

  char* ws = (char*)d_ws;
  short* Wt       = (short*)ws;
  unsigned* tab   = (unsigned*)(ws + 131072);
  float* sum      = (float*)(ws + 154624);
  float* ssq      = (float*)(ws + 178176);
  float* An2      = (float*)(ws + 201728);
  float* Bn2      = (float*)(ws + 225280);
  char* Wt8       = ws + WT8_OFF;
  unsigned* tab8  = (unsigned*)(ws + TAB8_OFF);
  unsigned* tab8b = (unsigned*)(ws + TAB8B_OFF);
  bool part = ws_size >= (size_t)WS_NEED;
  float* psum = part ? (float*)(ws + PSUM_OFF) : nullptr;
  float* pssq = part ? (float*)(ws + PSSQ_OFF) : nullptr;

  k_prep<<<256, 256, 0, stream>>>(W, mask, Wt, Wt8, tab, tab8, tab8b, sum);
  k_stats<<<256, 512, 0, stream>>>(x0, Wt8, tab8, tab8b, sum, ssq, psum, pssq);
  k_finalize<<<92, 256, 0, stream>>>(sum, ssq, psum, pssq, bnw, bnb, An2, Bn2);
  k_write<<<256, 512, 0, stream>>>(x0, Wt, tab, An2, Bn2, out);
}

// Round 17
// 241.019 us; speedup vs baseline: 1.1144x; 1.0007x over previous
//
#include <hip/hip_runtime.h>
#include <hip/hip_bf16.h>

#define NV 23
#define NTOT 16384
#define FLAT (NV * 256)    // 5888 floats per slab
#define FLAT4 (FLAT / 4)   // 1472
#define CH 184             // f32x4 per wave (1472/8)
#define NS 3               // reg slots per chunk (64+64+56)
#define SLAB 23552         // slab bytes

// stats: X48[2]@0 (24576, fp8 48x256B pair-tiles) | raw[4]@24576 (94208) -> 118784
// grid 256 x NB0=64 slabs (32 pairs)
#define NB0 64
#define ROFF0 24576
// write: X'[2]@0 (32768) | raw[3]@32768 (70656) | O@103424 -> 126976, grid 256 x NB1=64
#define NB1 64
#define ROFF1 32768
#define OOFF1 103424

#define NPART 256
#define PROWS 48           // psum rows per block (46 used)
#define WT8_OFF 248832
#define TAB8_OFF 314368
#define TAB8B_OFF 337920
#define PSUM_OFF 361472
#define PSSQ_OFF (PSUM_OFF + NPART * PROWS * 256 * 4)
#define WS_NEED (PSSQ_OFF + NPART * PROWS * 256 * 4)

typedef short s16x8 __attribute__((ext_vector_type(8)));
typedef float f32x4 __attribute__((ext_vector_type(4)));
typedef unsigned u32x4 __attribute__((ext_vector_type(4)));
typedef long long i64t;

// x/23 for 0 <= x < 61681
__device__ __forceinline__ int divNV(int x) { return (int)(((unsigned)x * 45591u) >> 20); }
// f32 -> bf16 bits, RNE
__device__ __forceinline__ unsigned f2bf(float f) {
  unsigned u = __float_as_uint(f);
  u += 0x7fffu + ((u >> 16) & 1u);
  return u >> 16;
}
// X' column swizzle (16-B granules): distinct groups for w-strides of 4
// (form writes ~conflict-free), 16-lane read groups 8 distinct slots (2-way, free).
__device__ __forceinline__ int fsw(int w) { return ((w + (w >> 3)) * 3) & 7; }

// async global->LDS DMA, 16B per lane (lds dest wave-uniform, HW adds lane*16)
__device__ __forceinline__ void gl_lds16(const void* g, void* l) {
  __builtin_amdgcn_global_load_lds(
      (const __attribute__((address_space(1))) unsigned*)(unsigned long long)(uintptr_t)g,
      (__attribute__((address_space(3))) unsigned*)(unsigned)(uintptr_t)l, 16, 0, 0);
}

// ws: Wt@0 | tab@131072 | sum@154624 | ssq@178176 | An2@201728 | Bn2@225280
//     | Wt8@248832 | tab8@314368 | tab8b@337920 | psum@361472 | pssq -> ~25.5MB
__global__ void k_prep(const float* __restrict__ W, const float* __restrict__ mask,
                       short* __restrict__ Wt, char* __restrict__ Wt8,
                       unsigned* __restrict__ tab, unsigned* __restrict__ tab8,
                       unsigned* __restrict__ tab8b, float* __restrict__ sums) {
  int idx = blockIdx.x * 256 + threadIdx.x;  // grid 256 -> 65536
  int d = idx >> 8, c = idx & 255;
  float wv = W[c * 256 + d];
  Wt[idx] = (short)f2bf(wv);                 // W^T bf16: Wt[d][c]
  Wt8[idx] = (char)__builtin_amdgcn_cvt_pk_fp8_f32(wv, wv, 0, false);  // e4m3
  if (idx < FLAT) {
    // p = idx = c*23 + v ; w = (v - c) mod 23
    int cc = divNV(idx);
    int v = idx - NV * cc;
    int cm = cc - NV * divNV(cc);
    int w = v - cm; w += (w >> 31) & NV;
    unsigned m2b = f2bf(tanhf(mask[(w << 8) + cc]) + 1.0f) << 16;
    tab[idx]   = m2b | (unsigned)((w << 9) + ((cc << 1) ^ (fsw(w) << 4)));      // bf16 X'
    tab8[idx]  = m2b | (unsigned)((w << 8) + (cc ^ (fsw(w) << 4)));             // fp8 row w
    tab8b[idx] = m2b | (unsigned)(((w + NV) << 8) + (cc ^ (fsw(w + NV) << 4))); // fp8 row w+23
  }
  if (idx < 2 * FLAT) sums[idx] = 0.0f;      // zero sum+ssq (atomic fallback)
}

// grid 92 x 256. Partial path: P[b][row<48][d]; feature (w,d) = rows w and w+23.
__global__ void k_finalize(const float* __restrict__ sum, const float* __restrict__ ssq,
                           const float* __restrict__ psum, const float* __restrict__ pssq,
                           const float* __restrict__ bnw, const float* __restrict__ bnb,
                           float* __restrict__ An2, float* __restrict__ Bn2) {
  __shared__ float red[2][4][64];
  const int t = threadIdx.x;
  const int f0 = blockIdx.x * 64;
  const int wq = f0 >> 8;                  // uniform w for this block
  const int dq = (f0 & 255);
  if (psum) {
    const int fl = t & 63, c = t >> 6;     // 4 chunks x 64 partials each
    size_t oA = (size_t)(wq << 8) + dq + fl;
    size_t oB = (size_t)((wq + NV) << 8) + dq + fl;
    float S = 0.f, Q = 0.f;
    for (int b = 0; b < 64; ++b) {
      size_t base = (size_t)(c * 64 + b) * (PROWS * 256);
      S += psum[base + oA] + psum[base + oB];
      Q += pssq[base + oA] + pssq[base + oB];
    }
    red[0][c][fl] = S;
    red[1][c][fl] = Q;
    __syncthreads();
  }
  if (t < 64) {
    int idx = f0 + t;
    float S, Q;
    if (psum) {
      S = red[0][0][t] + red[0][1][t] + red[0][2][t] + red[0][3][t];
      Q = red[1][0][t] + red[1][1][t] + red[1][2][t] + red[1][3][t];
    } else {
      S = sum[idx]; Q = ssq[idx];
    }
    int w = idx >> 8, d = idx & 255;
    float mean = S * (1.0f / NTOT);
    float var  = Q * (1.0f / NTOT) - mean * mean;
    float inv  = rsqrtf(var + 1e-5f);
    int i = w + d; i -= NV * divNV(i);       // out-shift row i = (w+d) % 23
    float a = inv * bnw[i * 256 + d];
    An2[d * NV + i] = a;
    Bn2[d * NV + i] = bnb[i * 256 + d] - mean * a;
  }
}

// Stats FP8 M=48 pair-tiles. R17: phase order = stage -> mstep(u) ->
// formpair(u+1) -> sstep. LDS ops complete in-order per wave, so R16's
// form-before-mstep put form's 24 scattered byte-writes on the first MFMA's
// lgkm wait every phase. Now mstep's A-reads issue into an empty lgkm queue
// (MFMAs start ~LDS-latency after the barrier) and form's traffic drains
// while the MFMAs execute; sstep (VALU on acc) covers the tail.
// Hazards: X48[u&1] overwrite by formpair(u+2) is after next bar (per-wave
// lgkm drain => all mstep(u) reads done); raw roles unchanged from R16.
__global__ __launch_bounds__(512) void k_stats(
    const float* __restrict__ x0, const char* __restrict__ Wt8,
    const unsigned* __restrict__ tab8, const unsigned* __restrict__ tab8b,
    float* __restrict__ sum, float* __restrict__ ssq,
    float* __restrict__ psum, float* __restrict__ pssq) {
  __shared__ char smem[118784];  // X48[2] | raw[4]

  const int tid = threadIdx.x;
  const int lane = tid & 63;
  const int wv = tid >> 6;
  const int l15 = lane & 15;
  const int lg = lane >> 4;
  const int d0 = wv * 32;
  const int ch0 = wv * CH;
  const int fr0 = fsw(l15) << 4;          // read swizzle rows l15, 16+l15, 32+l15
  const int fr1 = fsw(16 + l15) << 4;
  const int fr2 = fsw(32 + l15) << 4;

  // B fragments fp8 (32 VGPR): B[k=c][n=d] = Wt8[d][c]
  i64t bfr8[2][8];
#pragma unroll
  for (int nt = 0; nt < 2; ++nt)
#pragma unroll
    for (int kt = 0; kt < 8; ++kt)
      bfr8[nt][kt] = *(const i64t*)(Wt8 + (d0 + nt * 16 + l15) * 256 + kt * 32 + lg * 8);

  u32x4 tbrA[NS], tbrB[NS];
#pragma unroll
  for (int s = 0; s < NS; ++s)
    if (s * 64 + lane < CH) {
      tbrA[s] = *(const u32x4*)(tab8 + 4 * (ch0 + s * 64 + lane));
      tbrB[s] = *(const u32x4*)(tab8b + 4 * (ch0 + s * 64 + lane));
    }

  // zero rows 46,47 of both X48 buffers (512B each, never written again)
  if (tid < 256) {
    int b = tid >> 7;
    *(int*)(smem + b * 12288 + 11776 + (tid & 127) * 4) = 0;
  }

  float s1[3][2][4], s2[3][2][4];
#pragma unroll
  for (int mt = 0; mt < 3; ++mt)
#pragma unroll
    for (int nt = 0; nt < 2; ++nt)
#pragma unroll
      for (int r = 0; r < 4; ++r) { s1[mt][nt][r] = 0.f; s2[mt][nt][r] = 0.f; }

  const int nbase = blockIdx.x * NB0;

  auto stage = [&](int T) {  // 23 exact DMAs for slab T -> raw[T%4]
    if (T >= NB0) return;
    const char* gs = (const char*)(x0 + (size_t)(nbase + T) * FLAT);
    char* lb = smem + ROFF0 + (T % 4) * SLAB;
    gl_lds16(gs + (wv << 10) + lane * 16, lb + (wv << 10));
    gl_lds16(gs + ((8 + wv) << 10) + lane * 16, lb + ((8 + wv) << 10));
    if (wv < 7)
      gl_lds16(gs + ((16 + wv) << 10) + lane * 16, lb + ((16 + wv) << 10));
  };
  auto formpair = [&](int P) {  // slabs 2P,2P+1 -> X48[P&1]
    if (2 * P >= NB0) return;
    const char* ra = smem + ROFF0 + ((2 * P) % 4) * SLAB;
    const char* rb = smem + ROFF0 + ((2 * P + 1) % 4) * SLAB;
    char* xb = smem + (P & 1) * 12288;
#pragma unroll
    for (int s = 0; s < NS; ++s)
      if (s * 64 + lane < CH) {
        f32x4 xa = *(const f32x4*)(ra + (ch0 + s * 64 + lane) * 16);
        f32x4 xv = *(const f32x4*)(rb + (ch0 + s * 64 + lane) * 16);
        u32x4 ta = tbrA[s], tb = tbrB[s];
#pragma unroll
        for (int e = 0; e < 4; e += 2) {
          float a0 = xa[e] * __uint_as_float(ta[e] & 0xffff0000u);
          float a1 = xa[e + 1] * __uint_as_float(ta[e + 1] & 0xffff0000u);
          float b0 = xv[e] * __uint_as_float(tb[e] & 0xffff0000u);
          float b1 = xv[e + 1] * __uint_as_float(tb[e + 1] & 0xffff0000u);
          int ua = __builtin_amdgcn_cvt_pk_fp8_f32(a0, a1, 0, false);
          int ub = __builtin_amdgcn_cvt_pk_fp8_f32(b0, b1, 0, false);
          xb[ta[e] & 0xffffu] = (char)ua;
          xb[ta[e + 1] & 0xffffu] = (char)(ua >> 8);
          xb[tb[e] & 0xffffu] = (char)ub;
          xb[tb[e + 1] & 0xffffu] = (char)(ub >> 8);
        }
      }
  };
  auto mstep = [&](int P, f32x4 (*acc)[2]) {  // y48 = X48[P&1] * W8
    const char* xb = smem + (P & 1) * 12288;
#pragma unroll
    for (int mt = 0; mt < 3; ++mt) {
      const int row = mt * 16 + l15;
      const int fr = mt == 0 ? fr0 : (mt == 1 ? fr1 : fr2);
      i64t a[8];
#pragma unroll
      for (int kt = 0; kt < 8; ++kt)
        a[kt] = *(const i64t*)(xb + (row << 8) + ((kt * 32 + lg * 8) ^ fr));
#pragma unroll
      for (int kt = 0; kt < 8; ++kt)
#pragma unroll
        for (int nt = 0; nt < 2; ++nt)
          acc[mt][nt] = __builtin_amdgcn_mfma_f32_16x16x32_fp8_fp8(
              a[kt], bfr8[nt][kt], acc[mt][nt], 0, 0, 0);
    }
  };
  auto bar = []() {
    asm volatile("s_waitcnt lgkmcnt(0)" ::: "memory");
    __builtin_amdgcn_s_barrier();
    asm volatile("" ::: "memory");
  };

  // prologue: 4 slabs in flight, form pair 0
  stage(0); stage(1); stage(2); stage(3);
  asm volatile("s_waitcnt vmcnt(0)" ::: "memory");
  bar();
  formpair(0);

  for (int u = 0; u < NB0 / 2; ++u) {
    asm volatile("s_waitcnt vmcnt(0)" ::: "memory");  // prev phase's slabs landed
    bar();  // all waves: formpair(u) writes drained; prev X48/raw readers done
    stage(2 * u + 4); stage(2 * u + 5);
    f32x4 acc[3][2];
#pragma unroll
    for (int mt = 0; mt < 3; ++mt)
#pragma unroll
      for (int nt = 0; nt < 2; ++nt) acc[mt][nt] = (f32x4){0.f, 0.f, 0.f, 0.f};
    __builtin_amdgcn_s_setprio(1);
    mstep(u, acc);          // A-reads into empty lgkm queue -> MFMAs start fast
    __builtin_amdgcn_s_setprio(0);
    formpair(u + 1);        // raw reads + scattered writes drain under the MFMAs
#pragma unroll
    for (int mt = 0; mt < 3; ++mt)
#pragma unroll
      for (int nt = 0; nt < 2; ++nt)
#pragma unroll
        for (int r = 0; r < 4; ++r) {
          float y = acc[mt][nt][r];
          s1[mt][nt][r] += y;
          s2[mt][nt][r] += y * y;
        }
  }

  if (psum) {
    float* ps = psum + (size_t)blockIdx.x * (PROWS * 256);
    float* pq = pssq + (size_t)blockIdx.x * (PROWS * 256);
#pragma unroll
    for (int mt = 0; mt < 3; ++mt)
#pragma unroll
      for (int nt = 0; nt < 2; ++nt)
#pragma unroll
        for (int r = 0; r < 4; ++r) {
          int row = mt * 16 + lg * 4 + r;
          if (row < 46) {
            int d = d0 + nt * 16 + l15;
            __builtin_nontemporal_store(s1[mt][nt][r], ps + (row << 8) + d);
            __builtin_nontemporal_store(s2[mt][nt][r], pq + (row << 8) + d);
          }
        }
  } else {
#pragma unroll
    for (int mt = 0; mt < 3; ++mt)
#pragma unroll
      for (int nt = 0; nt < 2; ++nt)
#pragma unroll
        for (int r = 0; r < 4; ++r) {
          int row = mt * 16 + lg * 4 + r;
          if (row < 46) {
            int w = row - (row >= NV ? NV : 0);
            int d = d0 + nt * 16 + l15;
            atomicAdd(sum + (w << 8) + d, s1[mt][nt][r]);
            atomicAdd(ssq + (w << 8) + d, s2[mt][nt][r]);
          }
        }
  }
}

// Output pass: bf16, R14 verbatim (near HBM floor).
__global__ __launch_bounds__(512) void k_write(
    const float* __restrict__ x0, const short* __restrict__ Wt,
    const unsigned* __restrict__ tab,
    const float* __restrict__ An2, const float* __restrict__ Bn2,
    float* __restrict__ out) {
  __shared__ char smem[126976];  // X'[2] | raw[3] | O
  float* O = (float*)(smem + OOFF1);

  const int tid = threadIdx.x;
  const int lane = tid & 63;
  const int wv = tid >> 6;
  const int l15 = lane & 15;
  const int lg = lane >> 4;
  const int d0 = wv * 32;
  const int ch0 = wv * CH;
  const int fr0 = fsw(l15) << 4;
  const int fr1 = fsw(16 + l15) << 4;

  s16x8 bfr[2][8];
#pragma unroll
  for (int nt = 0; nt < 2; ++nt)
#pragma unroll
    for (int kt = 0; kt < 8; ++kt)
      bfr[nt][kt] = *(const s16x8*)(Wt + (d0 + nt * 16 + l15) * 256 + kt * 32 + lg * 8);

  u32x4 tbr[NS];
#pragma unroll
  for (int s = 0; s < NS; ++s)
    if (s * 64 + lane < CH) tbr[s] = *(const u32x4*)(tab + 4 * (ch0 + s * 64 + lane));

  f32x4 anr[NS], bnr[NS];
#pragma unroll
  for (int s = 0; s < NS; ++s)
    if (s * 64 + lane < CH) {
      anr[s] = *(const f32x4*)(An2 + 4 * (ch0 + s * 64 + lane));
      bnr[s] = *(const f32x4*)(Bn2 + 4 * (ch0 + s * 64 + lane));
    }

  for (int i = tid; i < 2304; i += 512) {
    int b = i >= 1152;
    *(int*)(smem + b * 16384 + 11776 + (i - b * 1152) * 4) = 0;
  }

  const int nbase = blockIdx.x * NB1;
  auto nmap = [&](int T) { return nbase + (NB1 - 1 - T); };  // reverse: L3 tail

  auto stage = [&](int T) {
    if (T >= NB1) return;
    const char* gs = (const char*)(x0 + (size_t)nmap(T) * FLAT);
    char* lb = smem + ROFF1 + (T % 3) * SLAB;
    gl_lds16(gs + (wv << 10) + lane * 16, lb + (wv << 10));
    gl_lds16(gs + ((8 + wv) << 10) + lane * 16, lb + ((8 + wv) << 10));
    if (wv < 7)
      gl_lds16(gs + ((16 + wv) << 10) + lane * 16, lb + ((16 + wv) << 10));
  };
  auto form = [&](int T) {
    if (T >= NB1) return;
    const char* rb = smem + ROFF1 + (T % 3) * SLAB;
    char* xb = smem + (T & 1) * 16384;
#pragma unroll
    for (int s = 0; s < NS; ++s)
      if (s * 64 + lane < CH) {
        f32x4 xv = *(const f32x4*)(rb + (ch0 + s * 64 + lane) * 16);
        u32x4 tb = tbr[s];
#pragma unroll
        for (int e = 0; e < 4; ++e) {
          unsigned tt = tb[e];
          *(short*)(xb + (tt & 0xffffu)) =
              (short)f2bf(xv[e] * __uint_as_float(tt & 0xffff0000u));
        }
      }
  };
  auto bar = []() {
    asm volatile("s_waitcnt lgkmcnt(0)" ::: "memory");
    __builtin_amdgcn_s_barrier();
    asm volatile("" ::: "memory");
  };

  stage(0); stage(1);
  asm volatile("s_waitcnt vmcnt(0)" ::: "memory");
  bar();
  form(0);

  for (int t = 0; t < NB1; ++t) {
    if (t) asm volatile("s_waitcnt vmcnt(3)" ::: "memory");
    else   asm volatile("s_waitcnt vmcnt(0)" ::: "memory");
    bar();
    stage(t + 2);
    form(t + 1);

    const char* xb = smem + (t & 1) * 16384;
    f32x4 acc[2][2];
#pragma unroll
    for (int mt = 0; mt < 2; ++mt)
#pragma unroll
      for (int nt = 0; nt < 2; ++nt) acc[mt][nt] = (f32x4){0.f, 0.f, 0.f, 0.f};
    __builtin_amdgcn_s_setprio(1);
#pragma unroll
    for (int kt = 0; kt < 8; ++kt) {
      s16x8 af[2];
      af[0] = *(const s16x8*)(xb + (l15 << 9) + ((kt * 64 + lg * 16) ^ fr0));
      af[1] = *(const s16x8*)(xb + ((16 + l15) << 9) + ((kt * 64 + lg * 16) ^ fr1));
#pragma unroll
      for (int mt = 0; mt < 2; ++mt)
#pragma unroll
        for (int nt = 0; nt < 2; ++nt)
          acc[mt][nt] = __builtin_amdgcn_mfma_f32_16x16x32_bf16(
              af[mt], bfr[nt][kt], acc[mt][nt], 0, 0, 0);
    }
    __builtin_amdgcn_s_setprio(0);

#pragma unroll
    for (int mt = 0; mt < 2; ++mt)
#pragma unroll
      for (int nt = 0; nt < 2; ++nt)
#pragma unroll
        for (int r = 0; r < 4; ++r) {
          int w = mt * 16 + lg * 4 + r;
          if (w < NV) {
            int d = d0 + nt * 16 + l15;
            int sj = w + d; sj -= NV * divNV(sj);
            O[d * NV + sj] = acc[mt][nt][r];
          }
        }
    const char* rb = smem + ROFF1 + (t % 3) * SLAB;
    float* og = out + (size_t)nmap(t) * FLAT;
#pragma unroll
    for (int s = 0; s < NS; ++s)
      if (s * 64 + lane < CH) {
        int i = ch0 + s * 64 + lane;
        f32x4 y = *(const f32x4*)(O + 4 * i);
        f32x4 sl = *(const f32x4*)(rb + i * 16);
        f32x4 o;
#pragma unroll
        for (int e = 0; e < 4; ++e)
          o[e] = fmaxf(fmaf(y[e], anr[s][e], bnr[s][e]) + sl[e], 0.0f);
        __builtin_nontemporal_store(o, (f32x4*)og + i);
      }
  }
}

extern "C" void kernel_launch(void* const* d_in, const int* in_sizes, int n_in,
                              void* d_out, int out_size, void* d_ws, size_t ws_size,
                              hipStream_t stream) {
  const float* x0   = (const float*)d_in[0];
  const float* W    = (const float*)d_in[1];
  // d_in[2] = bias: cancels inside BN -> unused
  const float* mask = (const float*)d_in[3];
  const float* bnw  = (const float*)d_in[4];
  const float* bnb  = (const float*)d_in[5];
  // d_in[6], d_in[7] = shift tables: folded into addressing
  float* out = (float*)d_out;

  char* ws = (char*)d_ws;
  short* Wt       = (short*)ws;
  unsigned* tab   = (unsigned*)(ws + 131072);
  float* sum      = (float*)(ws + 154624);
  float* ssq      = (float*)(ws + 178176);
  float* An2      = (float*)(ws + 201728);
  float* Bn2      = (float*)(ws + 225280);
  char* Wt8       = ws + WT8_OFF;
  unsigned* tab8  = (unsigned*)(ws + TAB8_OFF);
  unsigned* tab8b = (unsigned*)(ws + TAB8B_OFF);
  bool part = ws_size >= (size_t)WS_NEED;
  float* psum = part ? (float*)(ws + PSUM_OFF) : nullptr;
  float* pssq = part ? (float*)(ws + PSSQ_OFF) : nullptr;

  k_prep<<<256, 256, 0, stream>>>(W, mask, Wt, Wt8, tab, tab8, tab8b, sum);
  k_stats<<<256, 512, 0, stream>>>(x0, Wt8, tab8, tab8b, sum, ssq, psum, pssq);
  k_finalize<<<92, 256, 0, stream>>>(sum, ssq, psum, pssq, bnw, bnb, An2, Bn2);
  k_write<<<256, 512, 0, stream>>>(x0, Wt, tab, An2, Bn2, out);
}

// Round 20
// 238.530 us; speedup vs baseline: 1.1260x; 1.0104x over previous
//
#include <hip/hip_runtime.h>
#include <hip/hip_bf16.h>

#define NV 23
#define NTOT 16384
#define FLAT (NV * 256)    // 5888 floats per slab
#define FLAT4 (FLAT / 4)   // 1472
#define CH 184             // f32x4 per wave (1472/8)
#define NS 3               // reg slots per chunk (64+64+56)
#define SLAB 23552         // slab bytes

// stats: X48[2]@0 (24576) | raw[5]@24576 (117760) -> 142336; grid 256 x NB0=64
#define NB0 64
#define ROFF0 24576
// write: X'[2]@0 (32768) | raw[4]@32768 (94208) | O@126976 -> 150528; grid 256 x NB1=64
#define NB1 64
#define ROFF1 32768
#define OOFF1 126976

#define NPART 256
#define PROWS 48           // psum rows per block (46 used)
#define WT8_OFF 248832
#define TAB8_OFF 314368
#define TAB8B_OFF 337920
#define PSUM_OFF 361472
#define PSSQ_OFF (PSUM_OFF + NPART * PROWS * 256 * 4)
#define WS_NEED (PSSQ_OFF + NPART * PROWS * 256 * 4)

// Compiler-only ordering fence: pins VMEM issue order so counted-vmcnt
// ledgers are valid. Emits no instruction.
#define CB() asm volatile("" ::: "memory")

typedef short s16x8 __attribute__((ext_vector_type(8)));
typedef float f32x4 __attribute__((ext_vector_type(4)));
typedef unsigned u32x4 __attribute__((ext_vector_type(4)));
typedef long long i64t;

// x/23 for 0 <= x < 61681
__device__ __forceinline__ int divNV(int x) { return (int)(((unsigned)x * 45591u) >> 20); }
// f32 -> bf16 bits, RNE
__device__ __forceinline__ unsigned f2bf(float f) {
  unsigned u = __float_as_uint(f);
  u += 0x7fffu + ((u >> 16) & 1u);
  return u >> 16;
}
// X' column swizzle (16-B granules)
__device__ __forceinline__ int fsw(int w) { return ((w + (w >> 3)) * 3) & 7; }

// async global->LDS DMA, 16B per lane (lds dest wave-uniform, HW adds lane*16)
__device__ __forceinline__ void gl_lds16(const void* g, void* l) {
  __builtin_amdgcn_global_load_lds(
      (const __attribute__((address_space(1))) unsigned*)(unsigned long long)(uintptr_t)g,
      (__attribute__((address_space(3))) unsigned*)(unsigned)(uintptr_t)l, 16, 0, 0);
}

// ws: Wt@0 | tab@131072 | sum@154624 | ssq@178176 | An2@201728 | Bn2@225280
//     | Wt8@248832 | tab8@314368 | tab8b@337920 | psum@361472 | pssq -> ~25.5MB
__global__ void k_prep(const float* __restrict__ W, const float* __restrict__ mask,
                       short* __restrict__ Wt, char* __restrict__ Wt8,
                       unsigned* __restrict__ tab, unsigned* __restrict__ tab8,
                       unsigned* __restrict__ tab8b, float* __restrict__ sums) {
  int idx = blockIdx.x * 256 + threadIdx.x;  // grid 256 -> 65536
  int d = idx >> 8, c = idx & 255;
  float wv = W[c * 256 + d];
  Wt[idx] = (short)f2bf(wv);                 // W^T bf16: Wt[d][c]
  Wt8[idx] = (char)__builtin_amdgcn_cvt_pk_fp8_f32(wv, wv, 0, false);  // e4m3
  if (idx < FLAT) {
    // p = idx = c*23 + v ; w = (v - c) mod 23
    int cc = divNV(idx);
    int v = idx - NV * cc;
    int cm = cc - NV * divNV(cc);
    int w = v - cm; w += (w >> 31) & NV;
    unsigned m2b = f2bf(tanhf(mask[(w << 8) + cc]) + 1.0f) << 16;
    tab[idx]   = m2b | (unsigned)((w << 9) + ((cc << 1) ^ (fsw(w) << 4)));      // bf16 X'
    tab8[idx]  = m2b | (unsigned)((w << 8) + (cc ^ (fsw(w) << 4)));             // fp8 row w
    tab8b[idx] = m2b | (unsigned)(((w + NV) << 8) + (cc ^ (fsw(w + NV) << 4))); // fp8 row w+23
  }
  if (idx < 2 * FLAT) sums[idx] = 0.0f;      // zero sum+ssq (atomic fallback)
}

// grid 92 x 256. Partial path: P[b][row<48][d]; feature (w,d) = rows w and w+23.
__global__ void k_finalize(const float* __restrict__ sum, const float* __restrict__ ssq,
                           const float* __restrict__ psum, const float* __restrict__ pssq,
                           const float* __restrict__ bnw, const float* __restrict__ bnb,
                           float* __restrict__ An2, float* __restrict__ Bn2) {
  __shared__ float red[2][4][64];
  const int t = threadIdx.x;
  const int f0 = blockIdx.x * 64;
  const int wq = f0 >> 8;                  // uniform w for this block
  const int dq = (f0 & 255);
  if (psum) {
    const int fl = t & 63, c = t >> 6;     // 4 chunks x 64 partials each
    size_t oA = (size_t)(wq << 8) + dq + fl;
    size_t oB = (size_t)((wq + NV) << 8) + dq + fl;
    float S = 0.f, Q = 0.f;
    for (int b = 0; b < 64; ++b) {
      size_t base = (size_t)(c * 64 + b) * (PROWS * 256);
      S += psum[base + oA] + psum[base + oB];
      Q += pssq[base + oA] + pssq[base + oB];
    }
    red[0][c][fl] = S;
    red[1][c][fl] = Q;
    __syncthreads();
  }
  if (t < 64) {
    int idx = f0 + t;
    float S, Q;
    if (psum) {
      S = red[0][0][t] + red[0][1][t] + red[0][2][t] + red[0][3][t];
      Q = red[1][0][t] + red[1][1][t] + red[1][2][t] + red[1][3][t];
    } else {
      S = sum[idx]; Q = ssq[idx];
    }
    int w = idx >> 8, d = idx & 255;
    float mean = S * (1.0f / NTOT);
    float var  = Q * (1.0f / NTOT) - mean * mean;
    float inv  = rsqrtf(var + 1e-5f);
    int i = w + d; i -= NV * divNV(i);       // out-shift row i = (w+d) % 23
    float a = inv * bnw[i * 256 + d];
    An2[d * NV + i] = a;
    Bn2[d * NV + i] = bnb[i * 256 + d] - mean * a;
  }
}

// Stats FP8 M=48 pair-tiles, counted vmcnt. R20 fix: TAIL-AWARE waits —
// when the early stage is a no-op (2u+4 >= NB0) the counted allowance would
// cover STALE DMAs (R18/R19 race: formpair(31) read slab 63 in flight);
// use vmcnt(0) there (last 2 of 32 iterations, negligible cost).
__global__ __launch_bounds__(512) void k_stats(
    const float* __restrict__ x0, const char* __restrict__ Wt8,
    const unsigned* __restrict__ tab8, const unsigned* __restrict__ tab8b,
    float* __restrict__ sum, float* __restrict__ ssq,
    float* __restrict__ psum, float* __restrict__ pssq) {
  __shared__ char smem[142336];  // X48[2] | raw[5]

  const int tid = threadIdx.x;
  const int lane = tid & 63;
  const int wv = tid >> 6;
  const int l15 = lane & 15;
  const int lg = lane >> 4;
  const int d0 = wv * 32;
  const int ch0 = wv * CH;
  const int fr0 = fsw(l15) << 4;          // read swizzle rows l15, 16+l15, 32+l15
  const int fr1 = fsw(16 + l15) << 4;
  const int fr2 = fsw(32 + l15) << 4;

  // B fragments fp8 (32 VGPR): B[k=c][n=d] = Wt8[d][c]
  i64t bfr8[2][8];
#pragma unroll
  for (int nt = 0; nt < 2; ++nt)
#pragma unroll
    for (int kt = 0; kt < 8; ++kt)
      bfr8[nt][kt] = *(const i64t*)(Wt8 + (d0 + nt * 16 + l15) * 256 + kt * 32 + lg * 8);

  u32x4 tbrA[NS], tbrB[NS];
#pragma unroll
  for (int s = 0; s < NS; ++s)
    if (s * 64 + lane < CH) {
      tbrA[s] = *(const u32x4*)(tab8 + 4 * (ch0 + s * 64 + lane));
      tbrB[s] = *(const u32x4*)(tab8b + 4 * (ch0 + s * 64 + lane));
    }

  // zero rows 46,47 of both X48 buffers (512B each, never written again)
  if (tid < 256) {
    int b = tid >> 7;
    *(int*)(smem + b * 12288 + 11776 + (tid & 127) * 4) = 0;
  }

  float s1[3][2][4], s2[3][2][4];
#pragma unroll
  for (int mt = 0; mt < 3; ++mt)
#pragma unroll
    for (int nt = 0; nt < 2; ++nt)
#pragma unroll
      for (int r = 0; r < 4; ++r) { s1[mt][nt][r] = 0.f; s2[mt][nt][r] = 0.f; }

  const int nbase = blockIdx.x * NB0;

  auto stage = [&](int T) {  // 23 exact DMAs for slab T -> raw[T%5]; order-pinned
    if (T >= NB0) return;
    const char* gs = (const char*)(x0 + (size_t)(nbase + T) * FLAT);
    char* lb = smem + ROFF0 + (T % 5) * SLAB;
    gl_lds16(gs + (wv << 10) + lane * 16, lb + (wv << 10));
    gl_lds16(gs + ((8 + wv) << 10) + lane * 16, lb + ((8 + wv) << 10));
    if (wv < 7)
      gl_lds16(gs + ((16 + wv) << 10) + lane * 16, lb + ((16 + wv) << 10));
    CB();
  };
  auto formpair = [&](int P) {  // slabs 2P,2P+1 -> X48[P&1]
    if (2 * P >= NB0) return;
    const char* ra = smem + ROFF0 + ((2 * P) % 5) * SLAB;
    const char* rb = smem + ROFF0 + ((2 * P + 1) % 5) * SLAB;
    char* xb = smem + (P & 1) * 12288;
#pragma unroll
    for (int s = 0; s < NS; ++s)
      if (s * 64 + lane < CH) {
        f32x4 xa = *(const f32x4*)(ra + (ch0 + s * 64 + lane) * 16);
        f32x4 xv = *(const f32x4*)(rb + (ch0 + s * 64 + lane) * 16);
        u32x4 ta = tbrA[s], tb = tbrB[s];
#pragma unroll
        for (int e = 0; e < 4; e += 2) {
          float a0 = xa[e] * __uint_as_float(ta[e] & 0xffff0000u);
          float a1 = xa[e + 1] * __uint_as_float(ta[e + 1] & 0xffff0000u);
          float b0 = xv[e] * __uint_as_float(tb[e] & 0xffff0000u);
          float b1 = xv[e + 1] * __uint_as_float(tb[e + 1] & 0xffff0000u);
          int ua = __builtin_amdgcn_cvt_pk_fp8_f32(a0, a1, 0, false);
          int ub = __builtin_amdgcn_cvt_pk_fp8_f32(b0, b1, 0, false);
          xb[ta[e] & 0xffffu] = (char)ua;
          xb[ta[e + 1] & 0xffffu] = (char)(ua >> 8);
          xb[tb[e] & 0xffffu] = (char)ub;
          xb[tb[e + 1] & 0xffffu] = (char)(ub >> 8);
        }
      }
  };
  auto mstep = [&](int P, f32x4 (*acc)[2]) {  // y48 = X48[P&1] * W8
    const char* xb = smem + (P & 1) * 12288;
#pragma unroll
    for (int mt = 0; mt < 3; ++mt) {
      const int row = mt * 16 + l15;
      const int fr = mt == 0 ? fr0 : (mt == 1 ? fr1 : fr2);
      i64t a[8];
#pragma unroll
      for (int kt = 0; kt < 8; ++kt)
        a[kt] = *(const i64t*)(xb + (row << 8) + ((kt * 32 + lg * 8) ^ fr));
#pragma unroll
      for (int kt = 0; kt < 8; ++kt)
#pragma unroll
        for (int nt = 0; nt < 2; ++nt)
          acc[mt][nt] = __builtin_amdgcn_mfma_f32_16x16x32_fp8_fp8(
              a[kt], bfr8[nt][kt], acc[mt][nt], 0, 0, 0);
    }
  };
  auto bar = []() {
    asm volatile("s_waitcnt lgkmcnt(0)" ::: "memory");
    __builtin_amdgcn_s_barrier();
    asm volatile("" ::: "memory");
  };

  // prologue: slabs 0..3 -> slots 0..3
  stage(0); stage(1); stage(2); stage(3);
  asm volatile("s_waitcnt vmcnt(0)" ::: "memory");
  bar();
  formpair(0);

  for (int u = 0; u < NB0 / 2; ++u) {
    stage(2 * u + 4);   // EARLY: slot (2u-1)%5, readers finished >=1 bar ago
    if (2 * u + 4 < NB0) {
      // drain all but the just-issued stage (issue order pinned by CB)
      if (wv < 7) asm volatile("s_waitcnt vmcnt(3)" ::: "memory");
      else        asm volatile("s_waitcnt vmcnt(2)" ::: "memory");
    } else {
      // TAIL: stage was a no-op; counted allowance would spare stale DMAs
      asm volatile("s_waitcnt vmcnt(0)" ::: "memory");
    }
    bar();  // all waves: slabs <= 2u+3 visible; formpair(u) X48 writes drained
    stage(2 * u + 5);   // slot (2u)%5, freed by this bar
    f32x4 acc[3][2];
#pragma unroll
    for (int mt = 0; mt < 3; ++mt)
#pragma unroll
      for (int nt = 0; nt < 2; ++nt) acc[mt][nt] = (f32x4){0.f, 0.f, 0.f, 0.f};
    __builtin_amdgcn_s_setprio(1);
    mstep(u, acc);
    __builtin_amdgcn_s_setprio(0);
    formpair(u + 1);    // reads slots (2u+2)%5,(2u+3)%5; writes X48[(u+1)&1]
#pragma unroll
    for (int mt = 0; mt < 3; ++mt)
#pragma unroll
      for (int nt = 0; nt < 2; ++nt)
#pragma unroll
        for (int r = 0; r < 4; ++r) {
          float y = acc[mt][nt][r];
          s1[mt][nt][r] += y;
          s2[mt][nt][r] += y * y;
        }
  }

  if (psum) {
    float* ps = psum + (size_t)blockIdx.x * (PROWS * 256);
    float* pq = pssq + (size_t)blockIdx.x * (PROWS * 256);
#pragma unroll
    for (int mt = 0; mt < 3; ++mt)
#pragma unroll
      for (int nt = 0; nt < 2; ++nt)
#pragma unroll
        for (int r = 0; r < 4; ++r) {
          int row = mt * 16 + lg * 4 + r;
          if (row < 46) {
            int d = d0 + nt * 16 + l15;
            __builtin_nontemporal_store(s1[mt][nt][r], ps + (row << 8) + d);
            __builtin_nontemporal_store(s2[mt][nt][r], pq + (row << 8) + d);
          }
        }
  } else {
#pragma unroll
    for (int mt = 0; mt < 3; ++mt)
#pragma unroll
      for (int nt = 0; nt < 2; ++nt)
#pragma unroll
        for (int r = 0; r < 4; ++r) {
          int row = mt * 16 + lg * 4 + r;
          if (row < 46) {
            int w = row - (row >= NV ? NV : 0);
            int d = d0 + nt * 16 + l15;
            atomicAdd(sum + (w << 8) + d, s1[mt][nt][r]);
            atomicAdd(ssq + (w << 8) + d, s2[mt][nt][r]);
          }
        }
  }
}

// Output pass bf16, counted vmcnt + raw[4]. R20: tail-aware waits (t+2>=NB1
// -> vmcnt(0); R18/R19 race: form(63) read slab 63 in flight).
__global__ __launch_bounds__(512) void k_write(
    const float* __restrict__ x0, const short* __restrict__ Wt,
    const unsigned* __restrict__ tab,
    const float* __restrict__ An2, const float* __restrict__ Bn2,
    float* __restrict__ out) {
  __shared__ char smem[150528];  // X'[2] | raw[4] | O
  float* O = (float*)(smem + OOFF1);

  const int tid = threadIdx.x;
  const int lane = tid & 63;
  const int wv = tid >> 6;
  const int l15 = lane & 15;
  const int lg = lane >> 4;
  const int d0 = wv * 32;
  const int ch0 = wv * CH;
  const int fr0 = fsw(l15) << 4;
  const int fr1 = fsw(16 + l15) << 4;

  s16x8 bfr[2][8];
#pragma unroll
  for (int nt = 0; nt < 2; ++nt)
#pragma unroll
    for (int kt = 0; kt < 8; ++kt)
      bfr[nt][kt] = *(const s16x8*)(Wt + (d0 + nt * 16 + l15) * 256 + kt * 32 + lg * 8);

  u32x4 tbr[NS];
#pragma unroll
  for (int s = 0; s < NS; ++s)
    if (s * 64 + lane < CH) tbr[s] = *(const u32x4*)(tab + 4 * (ch0 + s * 64 + lane));

  f32x4 anr[NS], bnr[NS];
#pragma unroll
  for (int s = 0; s < NS; ++s)
    if (s * 64 + lane < CH) {
      anr[s] = *(const f32x4*)(An2 + 4 * (ch0 + s * 64 + lane));
      bnr[s] = *(const f32x4*)(Bn2 + 4 * (ch0 + s * 64 + lane));
    }

  for (int i = tid; i < 2304; i += 512) {
    int b = i >= 1152;
    *(int*)(smem + b * 16384 + 11776 + (i - b * 1152) * 4) = 0;
  }

  const int nbase = blockIdx.x * NB1;
  auto nmap = [&](int T) { return nbase + (NB1 - 1 - T); };  // reverse: L3 tail

  auto stage = [&](int T) {  // order-pinned
    if (T >= NB1) return;
    const char* gs = (const char*)(x0 + (size_t)nmap(T) * FLAT);
    char* lb = smem + ROFF1 + (T % 4) * SLAB;
    gl_lds16(gs + (wv << 10) + lane * 16, lb + (wv << 10));
    gl_lds16(gs + ((8 + wv) << 10) + lane * 16, lb + ((8 + wv) << 10));
    if (wv < 7)
      gl_lds16(gs + ((16 + wv) << 10) + lane * 16, lb + ((16 + wv) << 10));
    CB();
  };
  auto form = [&](int T) {
    if (T >= NB1) return;
    const char* rb = smem + ROFF1 + (T % 4) * SLAB;
    char* xb = smem + (T & 1) * 16384;
#pragma unroll
    for (int s = 0; s < NS; ++s)
      if (s * 64 + lane < CH) {
        f32x4 xv = *(const f32x4*)(rb + (ch0 + s * 64 + lane) * 16);
        u32x4 tb = tbr[s];
#pragma unroll
        for (int e = 0; e < 4; ++e) {
          unsigned tt = tb[e];
          *(short*)(xb + (tt & 0xffffu)) =
              (short)f2bf(xv[e] * __uint_as_float(tt & 0xffff0000u));
        }
      }
  };
  auto bar = []() {
    asm volatile("s_waitcnt lgkmcnt(0)" ::: "memory");
    __builtin_amdgcn_s_barrier();
    asm volatile("" ::: "memory");
  };

  stage(0); stage(1);
  asm volatile("s_waitcnt vmcnt(0)" ::: "memory");
  bar();
  form(0);

  for (int t = 0; t < NB1; ++t) {
    stage(t + 2);   // EARLY: slot (t+2)%4; last readers (phase t-2) done >=1 bar ago
    if (t + 2 < NB1) {
      // tolerate: 3 NT stores (epilogue t-1) + own just-issued stage (3|2);
      // pinned issue order => drains stage(t+1), needed by form(t+1).
      if (wv < 7) asm volatile("s_waitcnt vmcnt(6)" ::: "memory");
      else        asm volatile("s_waitcnt vmcnt(5)" ::: "memory");
    } else {
      // TAIL: stage was a no-op; counted allowance would spare stale DMAs
      asm volatile("s_waitcnt vmcnt(0)" ::: "memory");
    }
    bar();  // all waves: slab t+1 visible; X'(t) form writes drained
    form(t + 1);

    const char* xb = smem + (t & 1) * 16384;
    f32x4 acc[2][2];
#pragma unroll
    for (int mt = 0; mt < 2; ++mt)
#pragma unroll
      for (int nt = 0; nt < 2; ++nt) acc[mt][nt] = (f32x4){0.f, 0.f, 0.f, 0.f};
    __builtin_amdgcn_s_setprio(1);
#pragma unroll
    for (int kt = 0; kt < 8; ++kt) {
      s16x8 af[2];
      af[0] = *(const s16x8*)(xb + (l15 << 9) + ((kt * 64 + lg * 16) ^ fr0));
      af[1] = *(const s16x8*)(xb + ((16 + l15) << 9) + ((kt * 64 + lg * 16) ^ fr1));
#pragma unroll
      for (int mt = 0; mt < 2; ++mt)
#pragma unroll
        for (int nt = 0; nt < 2; ++nt)
          acc[mt][nt] = __builtin_amdgcn_mfma_f32_16x16x32_bf16(
              af[mt], bfr[nt][kt], acc[mt][nt], 0, 0, 0);
    }
    __builtin_amdgcn_s_setprio(0);

#pragma unroll
    for (int mt = 0; mt < 2; ++mt)
#pragma unroll
      for (int nt = 0; nt < 2; ++nt)
#pragma unroll
        for (int r = 0; r < 4; ++r) {
          int w = mt * 16 + lg * 4 + r;
          if (w < NV) {
            int d = d0 + nt * 16 + l15;
            int sj = w + d; sj -= NV * divNV(sj);
            O[d * NV + sj] = acc[mt][nt][r];
          }
        }
    const char* rb = smem + ROFF1 + (t % 4) * SLAB;
    float* og = out + (size_t)nmap(t) * FLAT;
#pragma unroll
    for (int s = 0; s < NS; ++s)
      if (s * 64 + lane < CH) {
        int i = ch0 + s * 64 + lane;
        f32x4 y = *(const f32x4*)(O + 4 * i);
        f32x4 sl = *(const f32x4*)(rb + i * 16);
        f32x4 o;
#pragma unroll
        for (int e = 0; e < 4; ++e)
          o[e] = fmaxf(fmaf(y[e], anr[s][e], bnr[s][e]) + sl[e], 0.0f);
        __builtin_nontemporal_store(o, (f32x4*)og + i);
      }
    CB();  // pin the 3 NT stores before next phase's early stage
  }
}

extern "C" void kernel_launch(void* const* d_in, const int* in_sizes, int n_in,
                              void* d_out, int out_size, void* d_ws, size_t ws_size,
                              hipStream_t stream) {
  const float* x0   = (const float*)d_in[0];
  const float* W    = (const float*)d_in[1];
  // d_in[2] = bias: cancels inside BN -> unused
  const float* mask = (const float*)d_in[3];
  const float* bnw  = (const float*)d_in[4];
  const float* bnb  = (const float*)d_in[5];
  // d_in[6], d_in[7] = shift tables: folded into addressing
  float* out = (float*)d_out;

  char* ws = (char*)d_ws;
  short* Wt       = (short*)ws;
  unsigned* tab   = (unsigned*)(ws + 131072);
  float* sum      = (float*)(ws + 154624);
  float* ssq      = (float*)(ws + 178176);
  float* An2      = (float*)(ws + 201728);
  float* Bn2      = (float*)(ws + 225280);
  char* Wt8       = ws + WT8_OFF;
  unsigned* tab8  = (unsigned*)(ws + TAB8_OFF);
  unsigned* tab8b = (unsigned*)(ws + TAB8B_OFF);
  bool part = ws_size >= (size_t)WS_NEED;
  float* psum = part ? (float*)(ws + PSUM_OFF) : nullptr;
  float* pssq = part ? (float*)(ws + PSSQ_OFF) : nullptr;

  k_prep<<<256, 256, 0, stream>>>(W, mask, Wt, Wt8, tab, tab8, tab8b, sum);
  k_stats<<<256, 512, 0, stream>>>(x0, Wt8, tab8, tab8b, sum, ssq, psum, pssq);
  k_finalize<<<92, 256, 0, stream>>>(sum, ssq, psum, pssq, bnw, bnb, An2, Bn2);
  k_write<<<256, 512, 0, stream>>>(x0, Wt, tab, An2, Bn2, out);
}